// Round 13
// baseline (11149.080 us; speedup 1.0000x reference)
//
#include <hip/hip_runtime.h>
#include <math.h>

#define HID 51
#define TMAIN 1024
#define FUT 64
#define TT (TMAIN + FUT)
#define RING 128   // h2 history ring depth (pow2)
#define RPAD 68    // h2 ring row stride in floats (16B-aligned)
#define H1R 8      // h1 ring depth (pow2)

typedef float v2f __attribute__((ext_vector_type(2)));

__device__ __forceinline__ float fast_sigmoid(float x) {
  return 1.0f / (1.0f + __expf(-x));
}
__device__ __forceinline__ float fast_tanh(float x) {
  return 1.0f - 2.0f / (__expf(2.0f * x) + 1.0f);
}

// ---- flag-based sync (LDS). Producer: data writes -> lgkmcnt(0) -> flag.
// Consumer: spin (volatile read) -> compiler fence -> data reads.
__device__ __forceinline__ void flag_publish(volatile int* f, bool lane0,
                                             int v) {
  asm volatile("s_waitcnt lgkmcnt(0)" ::: "memory");
  if (lane0) *f = v;
}
__device__ __forceinline__ void wait1(volatile int* f, int tgt) {
  while (*f < tgt) __builtin_amdgcn_s_sleep(1);
  asm volatile("" ::: "memory");
}
__device__ __forceinline__ void wait2(volatile int* a, volatile int* b,
                                      int tgt) {
  while (*a < tgt || *b < tgt) __builtin_amdgcn_s_sleep(1);
  asm volatile("" ::: "memory");
}

// Full-K 4-gate dot for ONE sequence: acc[g] += sum_k w[g][k] * h[k].
// h4[12] reads h[48..51]; element 51 in-bounds junk, unused.
__device__ __forceinline__ void dot4(const float* h, const v2f (&w2)[4][25],
                                     const float (&w50)[4], float (&acc)[4]) {
  const float4* h4 = reinterpret_cast<const float4*>(h);
  v2f s[4] = {{0.f, 0.f}, {0.f, 0.f}, {0.f, 0.f}, {0.f, 0.f}};
#pragma unroll
  for (int q = 0; q < 12; ++q) {
    float4 hv = h4[q];
    v2f lo = {hv.x, hv.y}, hi = {hv.z, hv.w};
#pragma unroll
    for (int g = 0; g < 4; ++g) {
      s[g] = __builtin_elementwise_fma(lo, w2[g][2 * q + 0], s[g]);
      s[g] = __builtin_elementwise_fma(hi, w2[g][2 * q + 1], s[g]);
    }
  }
  float4 ht = h4[12];
  v2f lo = {ht.x, ht.y};
#pragma unroll
  for (int g = 0; g < 4; ++g) {
    s[g] = __builtin_elementwise_fma(lo, w2[g][24], s[g]);
    acc[g] = fmaf(ht.z, w50[g], acc[g] + s[g].x + s[g].y);
  }
}

// Quarter dot: 4 gates x 26 K (13 float2 pairs) from a pre-offset pointer.
// K2 waves' pair 12 = {h[50], h[51]=0} x {W[50], 0}.
__device__ __forceinline__ void dotQ(const float* h, const v2f (&w)[4][13],
                                     float (&acc)[4]) {
  const float2* h2p = reinterpret_cast<const float2*>(h);
  v2f s[4] = {{0.f, 0.f}, {0.f, 0.f}, {0.f, 0.f}, {0.f, 0.f}};
#pragma unroll
  for (int p = 0; p < 13; ++p) {
    float2 hv = h2p[p];
    v2f a = {hv.x, hv.y};
#pragma unroll
    for (int g = 0; g < 4; ++g)
      s[g] = __builtin_elementwise_fma(a, w[g][p], s[g]);
  }
#pragma unroll
  for (int g = 0; g < 4; ++g) acc[g] = s[g].x + s[g].y;
}

// One block = TWO sequences, 8 waves, WAVE-LOCAL recurrences (R12 logic,
// which PASSED; R12's failure was register placement, not structure):
//   w0,w1: L1 cell, one seq each; lane u holds ALL 4 gate rows of Wh1.
//   w2,w3: L2 cell, one seq each (all 4 Wh2 rows / lane).
//   w4..w7: Wi2 quarters (seq x K-half) -> piK partials + lin-head flush.
// R12 lesson: "+v" pins on 204 floats/lane -> arch-VGPR demand > cap ->
// SCRATCH spill (7.2GB fetch). Fix: pin weights to AGPRs ("+a") -- the
// gfx950 unified file holds them (200 AGPR + ~55 VGPR < 256/wave at
// 8 waves, 1 block/CU), uses become accvgpr_read+fma (issue, not chain;
// R7 proved issue is not the limiter). The serial recurrences then have
// ZERO cross-wave sync; L1->Wi2->L2 hops stay pipelined via flags+rings
// (h1 8-deep, piK 4-deep, h2 128-deep), polls normally pre-satisfied.
__global__ __launch_bounds__(512, 2)
void lstm2_persistent(const float* __restrict__ input,
                      const float* __restrict__ Wi1,
                      const float* __restrict__ Wh1,
                      const float* __restrict__ bi1,
                      const float* __restrict__ bh1,
                      const float* __restrict__ Wi2,
                      const float* __restrict__ Wh2,
                      const float* __restrict__ bi2,
                      const float* __restrict__ bh2,
                      const float* __restrict__ Wlin,
                      const float* __restrict__ blin,
                      float* __restrict__ out) {
  __shared__ __align__(16) float lds_x[2][TMAIN];         // [seq][t]
  __shared__ __align__(16) float lds_h1[H1R][2][64];      // [slot][seq][u]
  __shared__ __align__(16) float lds_piK1[2][4][4][64];   // [seq][par][g][u]
  __shared__ __align__(16) float lds_piK2[2][4][4][64];   // [seq][par][g][u]
  __shared__ __align__(16) float lds_h2h[RING][2][RPAD];  // [slot][seq][u]
  __shared__ __align__(16) float lds_wlin[64];
  __shared__ __align__(16) float lds_outbuf[2][64];       // feedback outputs
  __shared__ float lds_lin[2];                            // out(t) feedback
  __shared__ float lds_fb[2];                             // out(1023) seed
  __shared__ int lds_flags[8];  // 0,1: L1 A/B  2,3: L2 A/B  4..7: Wi2

  volatile int* vf = (volatile int*)lds_flags;

  const int tid = threadIdx.x;
  const int s0 = blockIdx.x * 2;  // sequence pair
  const int wid = tid >> 6;       // 0..7
  const int lane = tid & 63;
  const bool act = lane < HID;
  const int u = act ? lane : (HID - 1);  // lane = unit (clamped)

  // Stage inputs; zero h1 ring (lanes 51..63 stay 0 forever -> dotQ tail
  // safe); zero h2 ring slot RING-1 (h2(-1)=0); stage wlin; init flags.
  for (int i = tid; i < TMAIN; i += 512) {
    lds_x[0][i] = input[s0 * TMAIN + i];
    lds_x[1][i] = input[(s0 + 1) * TMAIN + i];
  }
  if (tid < 128) {
#pragma unroll
    for (int p = 0; p < H1R; ++p) lds_h1[p][tid >> 6][tid & 63] = 0.0f;
    lds_h2h[RING - 1][tid >> 6][tid & 63] = 0.0f;
  }
  if (tid < 64) lds_wlin[tid] = (tid < HID) ? Wlin[tid] : 0.0f;
  if (tid < 8) lds_flags[tid] = -1;

  // ---- weights ----
  v2f w2f[4][25];   // full rows (L1 / L2 cell waves) -> pinned to AGPR
  float w50f[4] = {0.f, 0.f, 0.f, 0.f};
  v2f w2q[4][13];   // quarter rows (Wi2 waves) -> pinned to AGPR
  float bias[4] = {0.f, 0.f, 0.f, 0.f};
  float wi1g[4] = {0.f, 0.f, 0.f, 0.f};
  float wlin_u = 0.0f;
  float cst = 0.0f;  // cell state (L1 in w0/w1, L2 in w2/w3)

  if (wid < 4) {
    const float* Wsel = (wid < 2) ? Wh1 : Wh2;
#pragma unroll
    for (int g = 0; g < 4; ++g) {
      const float* row = Wsel + (g * HID + u) * HID;
#pragma unroll
      for (int p = 0; p < 25; ++p) {
        v2f t;
        t.x = row[2 * p + 0];
        t.y = row[2 * p + 1];
        w2f[g][p] = t;
      }
      w50f[g] = row[50];
    }
    if (wid < 2) {
#pragma unroll
      for (int g = 0; g < 4; ++g) {
        bias[g] = bi1[g * HID + u] + bh1[g * HID + u];
        wi1g[g] = Wi1[g * HID + u];
      }
    } else {
#pragma unroll
      for (int g = 0; g < 4; ++g)
        bias[g] = bi2[g * HID + u] + bh2[g * HID + u];
      wlin_u = Wlin[u];
    }
    // PIN weights to AGPRs: opaque defs (no remat) on the accumulator side
    // of the unified file (no arch-VGPR pressure, no scratch).
#pragma unroll
    for (int g = 0; g < 4; ++g) {
#pragma unroll
      for (int p = 0; p < 25; ++p) asm volatile("" : "+a"(w2f[g][p]));
      asm volatile("" : "+v"(w50f[g]), "+v"(bias[g]), "+v"(wi1g[g]));
    }
    asm volatile("" : "+v"(wlin_u));
  } else {
    const int kh = (wid - 4) & 1;      // 0 -> K[0,26), 1 -> K[26,51)
    const int koff = kh * 26;
#pragma unroll
    for (int g = 0; g < 4; ++g) {
      const float* row = Wi2 + (g * HID + u) * HID + koff;
      if (kh == 0) {
#pragma unroll
        for (int p = 0; p < 13; ++p) {
          v2f t;
          t.x = row[2 * p + 0];
          t.y = row[2 * p + 1];
          w2q[g][p] = t;
        }
      } else {
#pragma unroll
        for (int p = 0; p < 12; ++p) {
          v2f t;
          t.x = row[2 * p + 0];
          t.y = row[2 * p + 1];
          w2q[g][p] = t;
        }
        v2f t;
        t.x = row[24];  // K=50
        t.y = 0.0f;     // pairs with h1[51] == 0
        w2q[g][12] = t;
      }
    }
#pragma unroll
    for (int g = 0; g < 4; ++g)
#pragma unroll
      for (int p = 0; p < 13; ++p) asm volatile("" : "+a"(w2q[g][p]));
  }
  const float blin_s = blin[0];

  __syncthreads();  // staging + flags visible; last barrier before main

  // ================= barrier-free main phase =================
  if (wid < 2) {
    // L1 cell, seq = wid. Serial chain entirely intra-wave.
    const int seq = wid;
    volatile int* cons = vf + 4 + 2 * seq;  // this seq's Wi2 waves
    for (int k = 0; k < TMAIN; ++k) {
      if ((k & 3) == 0) wait2(cons, cons + 1, k - 5);  // h1 ring slack
      float x = lds_x[seq][k];
      float acc[4];
#pragma unroll
      for (int g = 0; g < 4; ++g) acc[g] = fmaf(x, wi1g[g], bias[g]);
      dot4(&lds_h1[(k - 1) & (H1R - 1)][seq][0], w2f, w50f, acc);
      float gi = fast_sigmoid(acc[0]);
      float gf = fast_sigmoid(acc[1]);
      float gg = fast_tanh(acc[2]);
      float go = fast_sigmoid(acc[3]);
      cst = gf * cst + gi * gg;
      float h = go * fast_tanh(cst);
      if (act) lds_h1[k & (H1R - 1)][seq][u] = h;
      flag_publish(vf + wid, lane == 0, k);
    }
  } else if (wid >= 4) {
    // Wi2 quarter: seq x K-half -> piK partials (+ lin-head flush on K1)
    const int seq = (wid - 4) >> 1;
    const int kh = (wid - 4) & 1;
    const int koff = kh * 26;
    volatile int* fL1 = vf + seq;
    volatile int* fL2 = vf + 2 + seq;
    for (int j = 0; j < TMAIN; ++j) {
      wait1(fL1, j);                         // h1(j) ready (normally ahead)
      if ((j & 1) == 0) wait1(fL2, j - 3);   // piK ring slack
      float acc[4];
      dotQ(&lds_h1[j & (H1R - 1)][seq][koff], w2q, acc);
      const int pm = j & 3;
      if (act) {
        float* dst = kh ? &lds_piK2[seq][pm][0][u] : &lds_piK1[seq][pm][0][u];
        dst[0] = acc[0];
        dst[64] = acc[1];
        dst[128] = acc[2];
        dst[192] = acc[3];
      }
      flag_publish(vf + wid, lane == 0, j);  // BEFORE flush (deadlock-free)
      if (kh == 0 && (j & 63) == 63) {
        // deferred linear head: 64 outputs, coalesced
        wait1(fL2, j);  // h2(c..c+63) written
        const int c = j - 63;
        const int m = c + lane;
        const float* r = &lds_h2h[m & (RING - 1)][seq][0];
        const float4* r4 = reinterpret_cast<const float4*>(r);
        const float4* w4 = reinterpret_cast<const float4*>(lds_wlin);
        float o0 = 0.f, o1 = 0.f, o2 = 0.f, o3 = 0.f;
#pragma unroll
        for (int q = 0; q < 12; ++q) {
          float4 rv = r4[q];
          float4 wv = w4[q];
          o0 = fmaf(rv.x, wv.x, o0);
          o1 = fmaf(rv.y, wv.y, o1);
          o2 = fmaf(rv.z, wv.z, o2);
          o3 = fmaf(rv.w, wv.w, o3);
        }
        o0 = fmaf(r[48], lds_wlin[48], o0);
        o1 = fmaf(r[49], lds_wlin[49], o1);
        o2 = fmaf(r[50], lds_wlin[50], o2);
        float o = (o0 + o1) + (o2 + o3) + blin_s;
        out[(s0 + seq) * TT + m] = o;
        if (m == TMAIN - 1) lds_fb[seq] = o;  // feedback seed
      }
    }
  } else {
    // L2 cell, seq = wid-2. Serial chain intra-wave; piK hop pipelined.
    const int seq = wid - 2;
    volatile int* prod = vf + 4 + 2 * seq;
    for (int m = 0; m < TMAIN; ++m) {
      wait2(prod, prod + 1, m);  // piK(m) ready (normally ahead)
      const int pm = m & 3;
      float acc[4];
#pragma unroll
      for (int g = 0; g < 4; ++g)
        acc[g] = bias[g] + lds_piK1[seq][pm][g][u] + lds_piK2[seq][pm][g][u];
      dot4(&lds_h2h[(m - 1) & (RING - 1)][seq][0], w2f, w50f, acc);
      float gi = fast_sigmoid(acc[0]);
      float gf = fast_sigmoid(acc[1]);
      float gg = fast_tanh(acc[2]);
      float go = fast_sigmoid(acc[3]);
      cst = gf * cst + gi * gg;
      float h = go * fast_tanh(cst);
      if (act) lds_h2h[m & (RING - 1)][seq][u] = h;
      flag_publish(vf + wid, lane == 0, m);
    }
  }

  __syncthreads();  // re-converge before the serial feedback phase

  // =============== feedback phase: 3 sub-phases, barriered ==============
  for (int t = TMAIN; t < TT; ++t) {
    float ph[4] = {0.f, 0.f, 0.f, 0.f};
    // --- A: L1 cell with feedback x; L2 waves pre-dot Wh2 @ h2(t-1) ---
    if (wid < 2) {
      const int seq = wid;
      float o = (t == TMAIN) ? lds_fb[seq] : lds_lin[seq];
      float acc[4];
#pragma unroll
      for (int g = 0; g < 4; ++g) acc[g] = fmaf(o, wi1g[g], bias[g]);
      dot4(&lds_h1[(t - 1) & (H1R - 1)][seq][0], w2f, w50f, acc);
      float gi = fast_sigmoid(acc[0]);
      float gf = fast_sigmoid(acc[1]);
      float gg = fast_tanh(acc[2]);
      float go = fast_sigmoid(acc[3]);
      cst = gf * cst + gi * gg;
      float h = go * fast_tanh(cst);
      if (act) lds_h1[t & (H1R - 1)][seq][u] = h;
    } else if (wid < 4) {
      dot4(&lds_h2h[(t - 1) & (RING - 1)][wid - 2][0], w2f, w50f, ph);
    }
    __syncthreads();
    // --- B: Wi2 quarters from h1(t) ---
    if (wid >= 4) {
      const int seq = (wid - 4) >> 1;
      const int kh = (wid - 4) & 1;
      float acc[4];
      dotQ(&lds_h1[t & (H1R - 1)][seq][kh * 26], w2q, acc);
      const int pm = t & 3;
      if (act) {
        float* dst = kh ? &lds_piK2[seq][pm][0][u] : &lds_piK1[seq][pm][0][u];
        dst[0] = acc[0];
        dst[64] = acc[1];
        dst[128] = acc[2];
        dst[192] = acc[3];
      }
    }
    __syncthreads();
    // --- C: L2 cell + butterfly linear head ---
    if (wid >= 2 && wid < 4) {
      const int seq = wid - 2;
      const int pm = t & 3;
      float acc[4];
#pragma unroll
      for (int g = 0; g < 4; ++g)
        acc[g] = bias[g] + lds_piK1[seq][pm][g][u] + lds_piK2[seq][pm][g][u] +
                 ph[g];
      float gi = fast_sigmoid(acc[0]);
      float gf = fast_sigmoid(acc[1]);
      float gg = fast_tanh(acc[2]);
      float go = fast_sigmoid(acc[3]);
      cst = gf * cst + gi * gg;
      float h = go * fast_tanh(cst);
      float val = 0.0f;
      if (act) {
        lds_h2h[t & (RING - 1)][seq][u] = h;
        val = wlin_u * h;
      }
#pragma unroll
      for (int off = 32; off >= 1; off >>= 1) val += __shfl_xor(val, off);
      if (lane == 0) {
        float o = val + blin_s;
        lds_lin[seq] = o;
        lds_outbuf[seq][t - TMAIN] = o;
      }
    }
    __syncthreads();
  }

  // epilogue: flush the 64 future outputs (coalesced)
  if (wid == 4 || wid == 6) {
    const int seq = (wid - 4) >> 1;
    out[(s0 + seq) * TT + TMAIN + lane] = lds_outbuf[seq][lane];
  }
}

extern "C" void kernel_launch(void* const* d_in, const int* in_sizes, int n_in,
                              void* d_out, int out_size, void* d_ws,
                              size_t ws_size, hipStream_t stream) {
  const float* input = (const float*)d_in[0];
  const float* Wi1 = (const float*)d_in[1];
  const float* Wh1 = (const float*)d_in[2];
  const float* bi1 = (const float*)d_in[3];
  const float* bh1 = (const float*)d_in[4];
  const float* Wi2 = (const float*)d_in[5];
  const float* Wh2 = (const float*)d_in[6];
  const float* bi2 = (const float*)d_in[7];
  const float* bh2 = (const float*)d_in[8];
  const float* Wlin = (const float*)d_in[9];
  const float* blin = (const float*)d_in[10];
  float* out = (float*)d_out;

  const int B = in_sizes[0] / TMAIN;  // 512
  lstm2_persistent<<<B / 2, 512, 0, stream>>>(input, Wi1, Wh1, bi1, bh1, Wi2,
                                              Wh2, bi2, bh2, Wlin, blin, out);
}

// Round 15
// 4090.832 us; speedup vs baseline: 2.7254x; 2.7254x over previous
//
#include <hip/hip_runtime.h>
#include <math.h>

#define HID 51
#define TMAIN 1024
#define FUT 64
#define TT (TMAIN + FUT)
#define RING 128   // h2 history ring depth (pow2)
#define RPAD 68    // h2 ring row stride in floats (16B-aligned)

typedef float v2f __attribute__((ext_vector_type(2)));

__device__ __forceinline__ float fast_sigmoid(float x) {
  return 1.0f / (1.0f + __expf(-x));
}
__device__ __forceinline__ float fast_tanh(float x) {
  return 1.0f - 2.0f / (__expf(2.0f * x) + 1.0f);
}

// Wave-local cell dot: acc[0..3] += Wh @ h for gates {i,f,o} from REGISTERS
// (w3[0]=i, w3[1]=f, w3[2]=o rows, 26 v2f pairs each covering k=0..51 with
// k=51 weight 0) and gate {g} STREAMED from LDS (layout [13][64][4]: lane u
// reads float4 [q][u][0..3] = W_g[u][4q..4q+3]; contiguous-across-lanes ->
// conflict-free). h read as uniform (broadcast) float4; h[51]==0 always.
__device__ __forceinline__ void cellDot(const float* h, const float* wg0,
                                        const v2f (&w3)[3][26],
                                        float (&acc)[4]) {
  const float4* h4 = reinterpret_cast<const float4*>(h);
  v2f sI = {0.f, 0.f}, sF = {0.f, 0.f}, sO = {0.f, 0.f}, sG = {0.f, 0.f};
#pragma unroll
  for (int q = 0; q < 13; ++q) {
    float4 hq = h4[q];
    float4 wg = *reinterpret_cast<const float4*>(wg0 + q * 256);
    v2f lo = {hq.x, hq.y}, hi = {hq.z, hq.w};
    sI = __builtin_elementwise_fma(lo, w3[0][2 * q + 0], sI);
    sI = __builtin_elementwise_fma(hi, w3[0][2 * q + 1], sI);
    sF = __builtin_elementwise_fma(lo, w3[1][2 * q + 0], sF);
    sF = __builtin_elementwise_fma(hi, w3[1][2 * q + 1], sF);
    sO = __builtin_elementwise_fma(lo, w3[2][2 * q + 0], sO);
    sO = __builtin_elementwise_fma(hi, w3[2][2 * q + 1], sO);
    v2f wlo = {wg.x, wg.y}, whi = {wg.z, wg.w};
    sG = __builtin_elementwise_fma(lo, wlo, sG);
    sG = __builtin_elementwise_fma(hi, whi, sG);
  }
  acc[0] += sI.x + sI.y;  // i
  acc[1] += sF.x + sF.y;  // f
  acc[2] += sG.x + sG.y;  // g (streamed)
  acc[3] += sO.x + sO.y;  // o
}

// Quarter dot: 4 gates x 26 K (13 float2 pairs) from a pre-offset pointer.
// K2 waves' pair 12 = {h[50], h[51]=0} x {W[50], 0}.
__device__ __forceinline__ void dotQ(const float* h, const v2f (&w)[4][13],
                                     float (&acc)[4]) {
  const float2* h2p = reinterpret_cast<const float2*>(h);
  v2f s[4] = {{0.f, 0.f}, {0.f, 0.f}, {0.f, 0.f}, {0.f, 0.f}};
#pragma unroll
  for (int p = 0; p < 13; ++p) {
    float2 hv = h2p[p];
    v2f a = {hv.x, hv.y};
#pragma unroll
    for (int g = 0; g < 4; ++g)
      s[g] = __builtin_elementwise_fma(a, w[g][p], s[g]);
  }
#pragma unroll
  for (int g = 0; g < 4; ++g) acc[g] = s[g].x + s[g].y;
}

// One block = TWO sequences, 8 waves, WAVE-LOCAL cells + MULTI-STEP
// BARRIER INTERVALS (R14 structure; R14's fail was the flush-wave bug:
// `wid<6` selected wid4+wid5 = BOTH seq0, so seq1 outputs were never
// stored and lds_fb[1] was junk -> absmax 4.6e-2 == typical |out|.
// Fixed: flush on kh==0 waves (wid4->seq0, wid6->seq1), matching the
// epilogue. Also zero the whole h2 ring (element 51 was uninit junk).):
//   w0,w1: L1 cell, one seq each (lane=unit; 3 gate-rows in regs, g-gate
//          streamed from LDS). NO cross-wave edge in the recurrence.
//   w2,w3: L2 cell, one seq each (same split).
//   w4..w7: Wi2 quarters (seq x K-half, 104 reg weights).
// Each interval = 4 timesteps; skew by WHOLE intervals:
//   interval iv: L1 k in [4iv,4iv+4) | Wi2 j in [4(iv-1),4iv) |
//                L2 m in [4(iv-2),4(iv-1)) | flush every 16 intervals.
// Consumers only read data >= 1 barrier old -> plain __syncthreads(), no
// flags (R11: per-hop flags lose to s_barrier). Barriers: 1027 -> 259.
// Ring slot disjointness: h1 8-deep (L1 writes {4iv..4iv+3}&7, Wi2 reads
// {4iv-4..4iv-1}&7 -- opposite halves); piK 8-deep (same argument);
// h2 128-deep (flush reads c..c+63, L2 writes c+64..c+67 -- disjoint).
__global__ __launch_bounds__(512, 2)
void lstm2_persistent(const float* __restrict__ input,
                      const float* __restrict__ Wi1,
                      const float* __restrict__ Wh1,
                      const float* __restrict__ bi1,
                      const float* __restrict__ bh1,
                      const float* __restrict__ Wi2,
                      const float* __restrict__ Wh2,
                      const float* __restrict__ bi2,
                      const float* __restrict__ bh2,
                      const float* __restrict__ Wlin,
                      const float* __restrict__ blin,
                      float* __restrict__ out) {
  __shared__ __align__(16) float lds_x[2][TMAIN];         // [seq][t]
  __shared__ __align__(16) float lds_h1[8][2][64];        // [slot][seq][u]
  __shared__ __align__(16) float lds_piK1[2][8][4][64];   // [seq][slot][g][u]
  __shared__ __align__(16) float lds_piK2[2][8][4][64];   // [seq][slot][g][u]
  __shared__ __align__(16) float lds_h2h[RING][2][RPAD];  // [slot][seq][u]
  __shared__ __align__(16) float lds_wg1[13][64][4];      // Wh1 g-gate stream
  __shared__ __align__(16) float lds_wg2[13][64][4];      // Wh2 g-gate stream
  __shared__ __align__(16) float lds_wlin[64];
  __shared__ __align__(16) float lds_outbuf[2][64];       // feedback outputs
  __shared__ float lds_lin[2];                            // out(t) feedback
  __shared__ float lds_fb[2];                             // out(1023) seed

  const int tid = threadIdx.x;
  const int s0 = blockIdx.x * 2;  // sequence pair
  const int wid = tid >> 6;       // 0..7
  const int lane = tid & 63;
  const bool act = lane < HID;
  const int u = act ? lane : (HID - 1);  // lane = unit (clamped)

  // ---- staging ----
  for (int i = tid; i < TMAIN; i += 512) {
    lds_x[0][i] = input[s0 * TMAIN + i];
    lds_x[1][i] = input[(s0 + 1) * TMAIN + i];
  }
  for (int i = tid; i < 8 * 2 * 64; i += 512)
    (&lds_h1[0][0][0])[i] = 0.0f;  // whole h1 ring zero (lanes 51..63 stay 0)
  for (int i = tid; i < RING * 2 * RPAD; i += 512)
    (&lds_h2h[0][0][0])[i] = 0.0f;  // whole h2 ring zero (elem 51.. junk-safe)
  if (tid < 64) lds_wlin[tid] = (tid < HID) ? Wlin[tid] : 0.0f;
  // g-gate streams, transposed: [q][u][j] = W[(2*HID+u)*HID + 4q+j] or 0
  for (int i = tid; i < 13 * 64 * 4; i += 512) {
    const int q = i >> 8, r = i & 255, uu = r >> 2, j = r & 3;
    const int k = 4 * q + j;
    const bool ok = (uu < HID) && (k < HID);
    (&lds_wg1[0][0][0])[i] = ok ? Wh1[(2 * HID + uu) * HID + k] : 0.0f;
    (&lds_wg2[0][0][0])[i] = ok ? Wh2[(2 * HID + uu) * HID + k] : 0.0f;
  }

  // ---- weights ----
  v2f w3[3][26];   // gates {i,f,o} rows (cell waves), k=0..51 (k51 -> 0)
  v2f w2q[4][13];  // quarter rows (Wi2 waves)
  float bias[4] = {0.f, 0.f, 0.f, 0.f};
  float wi1g[4] = {0.f, 0.f, 0.f, 0.f};
  float wlin_u = 0.0f;
  float cst = 0.0f;  // cell state (L1 in w0/w1, L2 in w2/w3)

  if (wid < 4) {
    const float* Wsel = (wid < 2) ? Wh1 : Wh2;
    const int gmap[3] = {0, 1, 3};  // i, f, o (g streamed)
#pragma unroll
    for (int gi = 0; gi < 3; ++gi) {
      const float* row = Wsel + (gmap[gi] * HID + u) * HID;
#pragma unroll
      for (int p = 0; p < 25; ++p) {
        v2f t;
        t.x = row[2 * p + 0];
        t.y = row[2 * p + 1];
        w3[gi][p] = t;
      }
      v2f t;
      t.x = row[50];
      t.y = 0.0f;  // pairs with h[51] == 0
      w3[gi][25] = t;
    }
    if (wid < 2) {
#pragma unroll
      for (int g = 0; g < 4; ++g) {
        bias[g] = bi1[g * HID + u] + bh1[g * HID + u];
        wi1g[g] = Wi1[g * HID + u];
      }
    } else {
#pragma unroll
      for (int g = 0; g < 4; ++g)
        bias[g] = bi2[g * HID + u] + bh2[g * HID + u];
      wlin_u = Wlin[u];
    }
    // PIN (prevents remat; 156 pinned floats + ~45 working < 256 cap)
#pragma unroll
    for (int gi = 0; gi < 3; ++gi)
#pragma unroll
      for (int p = 0; p < 26; ++p) asm volatile("" : "+v"(w3[gi][p]));
#pragma unroll
    for (int g = 0; g < 4; ++g)
      asm volatile("" : "+v"(bias[g]), "+v"(wi1g[g]));
    asm volatile("" : "+v"(wlin_u));
  } else {
    const int kh = (wid - 4) & 1;  // 0 -> K[0,26), 1 -> K[26,51)
    const int koff = kh * 26;
#pragma unroll
    for (int g = 0; g < 4; ++g) {
      const float* row = Wi2 + (g * HID + u) * HID + koff;
      if (kh == 0) {
#pragma unroll
        for (int p = 0; p < 13; ++p) {
          v2f t;
          t.x = row[2 * p + 0];
          t.y = row[2 * p + 1];
          w2q[g][p] = t;
        }
      } else {
#pragma unroll
        for (int p = 0; p < 12; ++p) {
          v2f t;
          t.x = row[2 * p + 0];
          t.y = row[2 * p + 1];
          w2q[g][p] = t;
        }
        v2f t;
        t.x = row[24];  // K=50
        t.y = 0.0f;     // pairs with h1[51] == 0
        w2q[g][12] = t;
      }
    }
#pragma unroll
    for (int g = 0; g < 4; ++g) {
#pragma unroll
      for (int p = 0; p < 13; ++p) asm volatile("" : "+v"(w2q[g][p]));
      asm volatile("" : "+v"(bias[g]));
    }
  }
  const float blin_s = blin[0];

  __syncthreads();

  // ======== main phase: 259 intervals x 4 steps, 1 barrier each ========
  for (int iv = 0; iv <= 258; ++iv) {
    if (wid < 2) {
      // L1 cell, seq = wid: 4 sequential steps, fully intra-wave.
      const int seq = wid;
      if (iv < 256) {
        const float* wg0 = &lds_wg1[0][u][0];
        for (int s = 0; s < 4; ++s) {
          const int k = 4 * iv + s;
          float x = lds_x[seq][k];
          float acc[4];
#pragma unroll
          for (int g = 0; g < 4; ++g) acc[g] = fmaf(x, wi1g[g], bias[g]);
          cellDot(&lds_h1[(k - 1) & 7][seq][0], wg0, w3, acc);
          float gi = fast_sigmoid(acc[0]);
          float gf = fast_sigmoid(acc[1]);
          float gg = fast_tanh(acc[2]);
          float go = fast_sigmoid(acc[3]);
          cst = gf * cst + gi * gg;
          float h = go * fast_tanh(cst);
          if (act) lds_h1[k & 7][seq][u] = h;
        }
      }
    } else if (wid < 4) {
      // L2 cell, seq = wid-2: consumes piK one interval old.
      const int seq = wid - 2;
      if (iv >= 2 && iv <= 257) {
        const float* wg0 = &lds_wg2[0][u][0];
        for (int s = 0; s < 4; ++s) {
          const int m = 4 * (iv - 2) + s;
          const int pm = m & 7;
          float acc[4];
#pragma unroll
          for (int g = 0; g < 4; ++g)
            acc[g] =
                bias[g] + lds_piK1[seq][pm][g][u] + lds_piK2[seq][pm][g][u];
          cellDot(&lds_h2h[(m - 1) & (RING - 1)][seq][0], wg0, w3, acc);
          float gi = fast_sigmoid(acc[0]);
          float gf = fast_sigmoid(acc[1]);
          float gg = fast_tanh(acc[2]);
          float go = fast_sigmoid(acc[3]);
          cst = gf * cst + gi * gg;
          float h = go * fast_tanh(cst);
          if (act) lds_h2h[m & (RING - 1)][seq][u] = h;
        }
      }
    } else {
      // Wi2 quarter: consumes h1 one interval old; flush every 16.
      const int seq = (wid - 4) >> 1;
      const int kh = (wid - 4) & 1;
      const int koff = kh * 26;
      if (iv >= 1 && iv <= 256) {
        for (int s = 0; s < 4; ++s) {
          const int j = 4 * (iv - 1) + s;
          float acc[4];
          dotQ(&lds_h1[j & 7][seq][koff], w2q, acc);
          const int pm = j & 7;
          if (act) {
            float* dst =
                kh ? &lds_piK2[seq][pm][0][u] : &lds_piK1[seq][pm][0][u];
            dst[0] = acc[0];
            dst[64] = acc[1];
            dst[128] = acc[2];
            dst[192] = acc[3];
          }
        }
      }
      // FLUSH: kh==0 wave of EACH seq (wid4 -> seq0, wid6 -> seq1).
      if (kh == 0 && iv >= 18 && ((iv - 2) & 15) == 0) {
        // flush chunk c..c+63 (h2 complete through 4(iv-2)-1 >= c+63)
        const int c = 4 * (iv - 2) - 64;
        const int m = c + lane;
        const float* r = &lds_h2h[m & (RING - 1)][seq][0];
        const float4* r4 = reinterpret_cast<const float4*>(r);
        const float4* w4 = reinterpret_cast<const float4*>(lds_wlin);
        float o0 = 0.f, o1 = 0.f, o2 = 0.f, o3 = 0.f;
#pragma unroll
        for (int q = 0; q < 12; ++q) {
          float4 rv = r4[q];
          float4 wv = w4[q];
          o0 = fmaf(rv.x, wv.x, o0);
          o1 = fmaf(rv.y, wv.y, o1);
          o2 = fmaf(rv.z, wv.z, o2);
          o3 = fmaf(rv.w, wv.w, o3);
        }
        o0 = fmaf(r[48], lds_wlin[48], o0);
        o1 = fmaf(r[49], lds_wlin[49], o1);
        o2 = fmaf(r[50], lds_wlin[50], o2);
        float o = (o0 + o1) + (o2 + o3) + blin_s;
        out[(s0 + seq) * TT + m] = o;
        if (m == TMAIN - 1) lds_fb[seq] = o;  // feedback seed
      }
    }
    __syncthreads();
  }

  // =============== feedback phase: 3 sub-phases, barriered ==============
  for (int t = TMAIN; t < TT; ++t) {
    float ph[4] = {0.f, 0.f, 0.f, 0.f};
    // --- A: L1 cell with feedback x; L2 waves pre-dot Wh2 @ h2(t-1) ---
    if (wid < 2) {
      const int seq = wid;
      float o = (t == TMAIN) ? lds_fb[seq] : lds_lin[seq];
      float acc[4];
#pragma unroll
      for (int g = 0; g < 4; ++g) acc[g] = fmaf(o, wi1g[g], bias[g]);
      cellDot(&lds_h1[(t - 1) & 7][seq][0], &lds_wg1[0][u][0], w3, acc);
      float gi = fast_sigmoid(acc[0]);
      float gf = fast_sigmoid(acc[1]);
      float gg = fast_tanh(acc[2]);
      float go = fast_sigmoid(acc[3]);
      cst = gf * cst + gi * gg;
      float h = go * fast_tanh(cst);
      if (act) lds_h1[t & 7][seq][u] = h;
    } else if (wid < 4) {
      cellDot(&lds_h2h[(t - 1) & (RING - 1)][wid - 2][0], &lds_wg2[0][u][0],
              w3, ph);
    }
    __syncthreads();
    // --- B: Wi2 quarters from h1(t) ---
    if (wid >= 4) {
      const int seq = (wid - 4) >> 1;
      const int kh = (wid - 4) & 1;
      float acc[4];
      dotQ(&lds_h1[t & 7][seq][kh * 26], w2q, acc);
      const int pm = t & 7;
      if (act) {
        float* dst = kh ? &lds_piK2[seq][pm][0][u] : &lds_piK1[seq][pm][0][u];
        dst[0] = acc[0];
        dst[64] = acc[1];
        dst[128] = acc[2];
        dst[192] = acc[3];
      }
    }
    __syncthreads();
    // --- C: L2 cell + butterfly linear head ---
    if (wid >= 2 && wid < 4) {
      const int seq = wid - 2;
      const int pm = t & 7;
      float acc[4];
#pragma unroll
      for (int g = 0; g < 4; ++g)
        acc[g] = bias[g] + lds_piK1[seq][pm][g][u] + lds_piK2[seq][pm][g][u] +
                 ph[g];
      float gi = fast_sigmoid(acc[0]);
      float gf = fast_sigmoid(acc[1]);
      float gg = fast_tanh(acc[2]);
      float go = fast_sigmoid(acc[3]);
      cst = gf * cst + gi * gg;
      float h = go * fast_tanh(cst);
      float val = 0.0f;
      if (act) {
        lds_h2h[t & (RING - 1)][seq][u] = h;
        val = wlin_u * h;
      }
#pragma unroll
      for (int off = 32; off >= 1; off >>= 1) val += __shfl_xor(val, off);
      if (lane == 0) {
        float o = val + blin_s;
        lds_lin[seq] = o;
        lds_outbuf[seq][t - TMAIN] = o;
      }
    }
    __syncthreads();
  }

  // epilogue: flush the 64 future outputs (coalesced)
  if (wid == 4 || wid == 6) {
    const int seq = (wid - 4) >> 1;
    out[(s0 + seq) * TT + TMAIN + lane] = lds_outbuf[seq][lane];
  }
}

extern "C" void kernel_launch(void* const* d_in, const int* in_sizes, int n_in,
                              void* d_out, int out_size, void* d_ws,
                              size_t ws_size, hipStream_t stream) {
  const float* input = (const float*)d_in[0];
  const float* Wi1 = (const float*)d_in[1];
  const float* Wh1 = (const float*)d_in[2];
  const float* bi1 = (const float*)d_in[3];
  const float* bh1 = (const float*)d_in[4];
  const float* Wi2 = (const float*)d_in[5];
  const float* Wh2 = (const float*)d_in[6];
  const float* bi2 = (const float*)d_in[7];
  const float* bh2 = (const float*)d_in[8];
  const float* Wlin = (const float*)d_in[9];
  const float* blin = (const float*)d_in[10];
  float* out = (float*)d_out;

  const int B = in_sizes[0] / TMAIN;  // 512
  lstm2_persistent<<<B / 2, 512, 0, stream>>>(input, Wi1, Wh1, bi1, bh1, Wi2,
                                              Wh2, bi2, bh2, Wlin, blin, out);
}